// Round 9
// baseline (389.807 us; speedup 1.0000x reference)
//
#include <hip/hip_runtime.h>

// 2-layer LSTM, B=1024 T=512 D=1 H=64. 512 blocks x 256 threads (4 waves), MB=2.
// Two independent blocks per CU (separate barrier domains): their phases drift
// to anti-phase, so one block's MFMA fills the other's in-order issue stalls.
// 8x row-dup: A row r = h[r&1] -> C row 4q+r = batch r&1 for every quad; every
// lane owns exactly ONE lstm_point (L=quad>>1, b=quad&1, unit=w*16+(lane&15)).
// 24 MFMA / 4 ds_read_b128 / ~55 VALU / 1 f16 write per wave-step; no shuffles.
// LDS H bytes: L*512 + par*256 + chunk*32 + b*16 + (unit&7)*2  (1 KiB total).
// t-loop unrolled x2 (compile-time parities), ini pipelined one step ahead,
// bias post-select (bsel). Peeled t=0 / t=512. One barrier per step.

typedef _Float16 f16x8 __attribute__((ext_vector_type(8)));
typedef float f32x4 __attribute__((ext_vector_type(4)));

#define TSTEPS 512
#define L2E 1.44269504088896340736f

__device__ __forceinline__ float lstm_point(float ai, float af, float ag, float ao,
                                            float& c) {
    // ai,af,ao pre-scaled by -log2e ; ag by +2log2e
    const float p  = __builtin_amdgcn_exp2f(ai);   // e^-i
    const float s_ = __builtin_amdgcn_exp2f(af);   // e^-f
    const float r_ = __builtin_amdgcn_exp2f(ag);   // e^2g
    const float v  = __builtin_amdgcn_exp2f(ao);   // e^-o
    const float m1 = (1.f + p) * (1.f + r_);
    const float R  = __builtin_amdgcn_rcpf(m1 * (1.f + s_));
    const float f  = m1 * R;                       // sigmoid(f)
    const float ig = (r_ - 1.f) * ((1.f + s_) * R);// sigmoid(i)*tanh(g)
    const float cc = __builtin_fmaf(f, c, ig);
    c = cc;
    const float w  = __builtin_amdgcn_exp2f(cc * (2.f * L2E));
    return (w - 1.f) * __builtin_amdgcn_rcpf((1.f + v) * (1.f + w));
}

__global__ __launch_bounds__(256, 2) void lstm2_kernel(
    const float* __restrict__ x,
    const float* __restrict__ W_ih0, const float* __restrict__ W_hh0,
    const float* __restrict__ b_ih0, const float* __restrict__ b_hh0,
    const float* __restrict__ W_ih1, const float* __restrict__ W_hh1,
    const float* __restrict__ b_ih1, const float* __restrict__ b_hh1,
    const float* __restrict__ W_fc,  const float* __restrict__ b_fc,
    float* __restrict__ out)
{
    __shared__ alignas(16) _Float16 H[512];         // 1 KiB, layout in header
    __shared__ alignas(16) float    xl[2][64][2];   // [buf][step][batch]

    const int tid  = (int)threadIdx.x;
    const int lane = tid & 63;
    const int w    = tid >> 6;          // wave: units w*16..w*16+15
    const int c    = lane & 15;
    const int quad = lane >> 4;         // 0..3
    const int L    = quad >> 1;         // lane's layer
    const int bq   = quad & 1;          // lane's batch
    const int j    = (w << 4) | c;      // lane's hidden unit
    const int b0   = (int)blockIdx.x * 2;

    // A-frag: element (row=c, k=quad*8+q) = h[c&1][k] ->
    //   byte = (k>>3)*32 + (c&1)*16 + (k&7)*2 = quad*32 + (c&1)*16 (+q*2)
    const int rdOff = quad * 32 + (c & 1) * 16;
    // write offset (excl. L/par): unit j, batch bq
    const int wOff0 = (j >> 3) * 32 + bq * 16 + (j & 7) * 2;

    // ---- per-lane weight fragments ----
    float biasc0[4], wih0c[4], biasc1[4];
    f16x8 bf0[4][2];              // W_hh0, K=64
    f16x8 bf1[4][4];              // [W_ih1 | W_hh1], K=128

#pragma unroll
    for (int g = 0; g < 4; ++g) {
        const int n = j + 64 * g;
        const float sg = (g == 2) ? (2.0f * L2E) : (-L2E);
        biasc0[g] = sg * (b_ih0[n] + b_hh0[n]);
        wih0c[g]  = sg * W_ih0[n];                 // D == 1
        biasc1[g] = sg * (b_ih1[n] + b_hh1[n]);
#pragma unroll
        for (int kb = 0; kb < 2; ++kb) {
            const float* p = W_hh0 + n * 64 + kb * 32 + quad * 8;
#pragma unroll
            for (int q = 0; q < 8; ++q) bf0[g][kb][q] = (_Float16)(p[q] * sg);
        }
#pragma unroll
        for (int kb = 0; kb < 4; ++kb) {
            const int kk = kb * 32 + quad * 8;
            const float* p = (kk < 64) ? (W_ih1 + n * 64 + kk)
                                       : (W_hh1 + n * 64 + (kk - 64));
#pragma unroll
            for (int q = 0; q < 8; ++q) bf1[g][kb][q] = (_Float16)(p[q] * sg);
        }
    }

    // bias selected once per lane (applied post-select each step)
    float bsel[4];
#pragma unroll
    for (int g = 0; g < 4; ++g) bsel[g] = L ? biasc1[g] : biasc0[g];

    // zero-init H + stage x chunk 0
    for (int i = tid; i < 512; i += 256) H[i] = (_Float16)0.f;
    if (tid < 128) {
        const int i = tid >> 1, m = tid & 1;
        xl[0][i][m] = x[(b0 + m) * TSTEPS + i];
    }
    __syncthreads();

    float cst = 0.f;             // cell state for this lane's (L, bq, j)

    // ---- peel t=0: h0(0) = lstm(bias + x0*w_ih); L0 lanes own it ----
    {
        const float xq = xl[0][0][bq];
        float tmp = 0.f;
        const float hv = lstm_point(__builtin_fmaf(xq, wih0c[0], biasc0[0]),
                                    __builtin_fmaf(xq, wih0c[1], biasc0[1]),
                                    __builtin_fmaf(xq, wih0c[2], biasc0[2]),
                                    __builtin_fmaf(xq, wih0c[3], biasc0[3]), tmp);
        if (L == 0) {
            cst = tmp;
            *(_Float16*)((char*)H + wOff0) = (_Float16)hv;   // L=0, par=0
        }
    }
    __syncthreads();

    // precomputed pointers
    char* Hc = (char*)H;
    const char* rdBase = Hc + rdOff;
    // layout: L*512 + par*256 (+ tile offsets)
    // half A (t odd):  read h0 par0 @0,     h1 par1 @768 ; write L0 par1 @256, L1 par0 @512
    // half B (t even): read h0 par1 @256,   h1 par0 @512 ; write L0 par0 @0,   L1 par1 @768
    char* wA = Hc + (L ? 512 : 256) + wOff0;
    char* wB = Hc + (L ? 768 : 0)   + wOff0;

    const f32x4 zf4 = {0.f, 0.f, 0.f, 0.f};
    auto STEP = [&](int h0imm, int h1imm, char* wp, const f32x4 (&ini)[4]) {
        const f16x8 a0 = *(const f16x8*)(rdBase + h0imm);
        const f16x8 a1 = *(const f16x8*)(rdBase + h0imm + 128);
        const f16x8 a2 = *(const f16x8*)(rdBase + h1imm);
        const f16x8 a3 = *(const f16x8*)(rdBase + h1imm + 128);
        float gate[4];
#pragma unroll
        for (int g = 0; g < 4; ++g) {
            // layer0, step t: C row 4q+r = batch r&1
            f32x4 A = __builtin_amdgcn_mfma_f32_16x16x32_f16(a0, bf0[g][0], ini[g], 0, 0, 0);
            A = __builtin_amdgcn_mfma_f32_16x16x32_f16(a1, bf0[g][1], A, 0, 0, 0);
            // layer1, step t-1 (shares a0,a1 = h0(t-1))
            f32x4 Bq = __builtin_amdgcn_mfma_f32_16x16x32_f16(a0, bf1[g][0], zf4, 0, 0, 0);
            Bq = __builtin_amdgcn_mfma_f32_16x16x32_f16(a1, bf1[g][1], Bq, 0, 0, 0);
            Bq = __builtin_amdgcn_mfma_f32_16x16x32_f16(a2, bf1[g][2], Bq, 0, 0, 0);
            Bq = __builtin_amdgcn_mfma_f32_16x16x32_f16(a3, bf1[g][3], Bq, 0, 0, 0);
            const float vA = bq ? A[1]  : A[0];
            const float vB = bq ? Bq[1] : Bq[0];
            gate[g] = (L ? vB : vA) + bsel[g];
        }
        const float hv = lstm_point(gate[0], gate[1], gate[2], gate[3], cst);
        *(_Float16*)wp = (_Float16)hv;
    };
    auto INI = [&](int t, f32x4 (&ini)[4]) {
        const float xv0 = xl[(t >> 6) & 1][t & 63][0];
        const float xv1 = xl[(t >> 6) & 1][t & 63][1];
#pragma unroll
        for (int g = 0; g < 4; ++g) {
            const float f0 = xv0 * wih0c[g];
            const float f1 = xv1 * wih0c[g];
            ini[g][0] = f0; ini[g][1] = f1; ini[g][2] = f0; ini[g][3] = f1;
        }
    };

    f32x4 iniN[4];
    INI(1, iniN);

    // ---- steady pairs: (t, t+1) for t = 1,3,...,509 ----
    for (int t = 1; t <= 509; t += 2) {
        // half A (t odd)
        f32x4 iniB[4];
        INI(t + 1, iniB);                          // independent: fills shadows
        STEP(0, 768, wA, iniN);
        __syncthreads();

        // half B (t+1 even)
        const int tB = t + 1;
        if ((tB & 63) == 32 && tB < 448 && tid < 128) {  // stage next x chunk
            const int cn = (tB >> 6) + 1;
            const int i = tid >> 1, m = tid & 1;
            xl[cn & 1][i][m] = x[(b0 + m) * TSTEPS + cn * 64 + i];
        }
        INI(t + 2, iniN);                          // next pair's half A = step t+2
        STEP(256, 512, wB, iniB);
        __syncthreads();
    }

    // ---- t = 511 (odd, half-A parities), uses iniN = INI(511) ----
    STEP(0, 768, wA, iniN);
    __syncthreads();

    // ---- peel t=512: h1(511) only; reads h0(511)@256, h1(510)@512 ----
    {
        const f16x8 a0 = *(const f16x8*)(rdBase + 256);
        const f16x8 a1 = *(const f16x8*)(rdBase + 384);
        const f16x8 a2 = *(const f16x8*)(rdBase + 512);
        const f16x8 a3 = *(const f16x8*)(rdBase + 640);
        float gate[4];
#pragma unroll
        for (int g = 0; g < 4; ++g) {
            f32x4 Bq = __builtin_amdgcn_mfma_f32_16x16x32_f16(a0, bf1[g][0], zf4, 0, 0, 0);
            Bq = __builtin_amdgcn_mfma_f32_16x16x32_f16(a1, bf1[g][1], Bq, 0, 0, 0);
            Bq = __builtin_amdgcn_mfma_f32_16x16x32_f16(a2, bf1[g][2], Bq, 0, 0, 0);
            Bq = __builtin_amdgcn_mfma_f32_16x16x32_f16(a3, bf1[g][3], Bq, 0, 0, 0);
            gate[g] = (bq ? Bq[1] : Bq[0]) + biasc1[g];
        }
        float tmp = cst;
        const float hv = lstm_point(gate[0], gate[1], gate[2], gate[3], tmp);
        if (L == 1)
            *(_Float16*)(Hc + 768 + wOff0) = (_Float16)hv;   // L=1, par=1
    }
    __syncthreads();

    // ---- epilogue: h0(511) @ 256, h1(511) @ 768 ----
    if (tid < 4) {
        const int which = tid >> 1, b = tid & 1;
        const char* hb = Hc + which * 512 + 256;
        float s = b_fc[0];
        for (int jj = 0; jj < 64; ++jj) {
            const int off = (jj >> 3) * 32 + b * 16 + (jj & 7) * 2;
            s += (float)*(const _Float16*)(hb + off) * W_fc[jj];
        }
        out[which * 1024 + b0 + b] = s;
    }
}

extern "C" void kernel_launch(void* const* d_in, const int* in_sizes, int n_in,
                              void* d_out, int out_size, void* d_ws, size_t ws_size,
                              hipStream_t stream) {
    (void)in_sizes; (void)n_in; (void)d_ws; (void)ws_size; (void)out_size;
    lstm2_kernel<<<512, 256, 0, stream>>>(
        (const float*)d_in[0],
        (const float*)d_in[1], (const float*)d_in[2],
        (const float*)d_in[3], (const float*)d_in[4],
        (const float*)d_in[5], (const float*)d_in[6],
        (const float*)d_in[7], (const float*)d_in[8],
        (const float*)d_in[9], (const float*)d_in[10],
        (float*)d_out);
}

// Round 10
// 285.901 us; speedup vs baseline: 1.3634x; 1.3634x over previous
//
#include <hip/hip_runtime.h>

// 2-layer LSTM, B=1024 T=512 D=1 H=64. 256 blocks x 512 threads (8 waves), MB=4.
// WAVE ROLE-SPLIT: waves 0-3 = layer0 recurrence (8 MFMA + INI + x-staging),
// waves 4-7 = layer1 (16 MFMA). Each SIMD gets one L0 + one L1 wave with
// ASYMMETRIC instruction mixes -> MFMA pipe of one overlaps VALU/trans tail of
// the other (m114 regime). Same total MFMA/VALU per SIMD as R7, minus the
// serialization. setprio(1) around MFMA clusters (T5-positive: role diversity).
// 4x row-dup (A row r = h[r&3], C row 4q+r = batch r): lane's point = batch
// quad, unit w*16+(lane&15); gate = own C-reg A[quad] via 3 cndmask; 0 shuffles.
// LDS H bytes: L*1024 + par*512 + chunk*64 + b*16 + (u&7)*2 (2 KiB, as R5/R7).
// t-loop unrolled x2 (compile-time parities), ini pipelined ahead (L0 waves).
// Peeled t=0 (L0) / t=512 (L1). One barrier per step.

typedef _Float16 f16x8 __attribute__((ext_vector_type(8)));
typedef float f32x4 __attribute__((ext_vector_type(4)));

#define TSTEPS 512
#define L2E 1.44269504088896340736f

__device__ __forceinline__ float lstm_point(float ai, float af, float ag, float ao,
                                            float& c) {
    // ai,af,ao pre-scaled by -log2e ; ag by +2log2e
    const float p  = __builtin_amdgcn_exp2f(ai);   // e^-i
    const float s_ = __builtin_amdgcn_exp2f(af);   // e^-f
    const float r_ = __builtin_amdgcn_exp2f(ag);   // e^2g
    const float v  = __builtin_amdgcn_exp2f(ao);   // e^-o
    const float m1 = (1.f + p) * (1.f + r_);
    const float R  = __builtin_amdgcn_rcpf(m1 * (1.f + s_));
    const float f  = m1 * R;                       // sigmoid(f)
    const float ig = (r_ - 1.f) * ((1.f + s_) * R);// sigmoid(i)*tanh(g)
    const float cc = __builtin_fmaf(f, c, ig);
    c = cc;
    const float w  = __builtin_amdgcn_exp2f(cc * (2.f * L2E));
    return (w - 1.f) * __builtin_amdgcn_rcpf((1.f + v) * (1.f + w));
}

__global__ __launch_bounds__(512, 2) void lstm2_kernel(
    const float* __restrict__ x,
    const float* __restrict__ W_ih0, const float* __restrict__ W_hh0,
    const float* __restrict__ b_ih0, const float* __restrict__ b_hh0,
    const float* __restrict__ W_ih1, const float* __restrict__ W_hh1,
    const float* __restrict__ b_ih1, const float* __restrict__ b_hh1,
    const float* __restrict__ W_fc,  const float* __restrict__ b_fc,
    float* __restrict__ out)
{
    __shared__ alignas(16) _Float16 H[2][2][256];   // L*1024 + par*512 + ...
    __shared__ alignas(16) float    xl[2][64][4];   // [buf][step][batch]

    const int tid  = (int)threadIdx.x;
    const int lane = tid & 63;
    const int wid  = tid >> 6;          // 0..7
    const int RL   = wid >> 2;          // 0 = layer0 waves, 1 = layer1 waves
    const int sw   = wid & 3;           // sub-wave: units sw*16..sw*16+15
    const int c    = lane & 15;
    const int quad = lane >> 4;         // 0..3 ; lane's batch = quad
    const int j    = (sw << 4) | c;     // lane's hidden unit
    const int b0   = (int)blockIdx.x * 4;

    const int rdOff = quad * 64 + (c & 3) * 16;      // A-frag: h[c&3][quad*8+q]
    const int wOff  = (j >> 3) * 64 + quad * 16 + (j & 7) * 2;   // (batch=quad)

    // ---- per-role weight fragments ----
    float biasc0[4], wih0c[4];
    f32x4 cini1[4];
    f16x8 bfA[4][2];              // L0 role: W_hh0, K=64
    f16x8 bfB[4][4];              // L1 role: [W_ih1 | W_hh1], K=128

    if (RL == 0) {
#pragma unroll
        for (int g = 0; g < 4; ++g) {
            const int n = j + 64 * g;
            const float sg = (g == 2) ? (2.0f * L2E) : (-L2E);
            biasc0[g] = sg * (b_ih0[n] + b_hh0[n]);
            wih0c[g]  = sg * W_ih0[n];             // D == 1
#pragma unroll
            for (int kb = 0; kb < 2; ++kb) {
                const float* p = W_hh0 + n * 64 + kb * 32 + quad * 8;
#pragma unroll
                for (int q = 0; q < 8; ++q) bfA[g][kb][q] = (_Float16)(p[q] * sg);
            }
        }
    } else {
#pragma unroll
        for (int g = 0; g < 4; ++g) {
            const int n = j + 64 * g;
            const float sg = (g == 2) ? (2.0f * L2E) : (-L2E);
            const float bb1 = sg * (b_ih1[n] + b_hh1[n]);
            cini1[g][0] = bb1; cini1[g][1] = bb1; cini1[g][2] = bb1; cini1[g][3] = bb1;
#pragma unroll
            for (int kb = 0; kb < 4; ++kb) {
                const int kk = kb * 32 + quad * 8;
                const float* p = (kk < 64) ? (W_ih1 + n * 64 + kk)
                                           : (W_hh1 + n * 64 + (kk - 64));
#pragma unroll
                for (int q = 0; q < 8; ++q) bfB[g][kb][q] = (_Float16)(p[q] * sg);
            }
        }
    }

    // zero-init H + stage x chunk 0 (L0 waves, coalesced per wave)
    for (int i = tid; i < 1024; i += 512) ((_Float16*)H)[i] = (_Float16)0.f;
    if (tid < 256) {
        xl[0][lane][wid] = x[(b0 + wid) * TSTEPS + lane];
    }
    __syncthreads();

    float cst = 0.f;   // cell state for this lane's point

    // ---- peel t=0: h0(0) = lstm(bias + x0*w_ih); L0 waves own it ----
    if (RL == 0) {
        const float xq = xl[0][0][quad];
        const float hv = lstm_point(__builtin_fmaf(xq, wih0c[0], biasc0[0]),
                                    __builtin_fmaf(xq, wih0c[1], biasc0[1]),
                                    __builtin_fmaf(xq, wih0c[2], biasc0[2]),
                                    __builtin_fmaf(xq, wih0c[3], biasc0[3]), cst);
        *(_Float16*)((char*)H + wOff) = (_Float16)hv;    // L=0, par=0
    }
    __syncthreads();

    char* Hc = (char*)H;
    const char* rdBase = Hc + rdOff;
    // half A (t odd):  pr=0 pr1=1 : L0 reads h0@0,   writes @512 ; L1 reads h0@0,   h1@1536, writes @1024
    // half B (t even): pr=1 pr1=0 : L0 reads h0@512, writes @0   ; L1 reads h0@512, h1@1024, writes @1536
    char* w0A = Hc + 512  + wOff;
    char* w0B = Hc + 0    + wOff;
    char* w1A = Hc + 1024 + wOff;
    char* w1B = Hc + 1536 + wOff;

    auto SEL = [&](const f32x4& A) -> float {      // pick C-reg = lane's batch (quad)
        const float x01 = (quad & 1) ? A[1] : A[0];
        const float x23 = (quad & 1) ? A[3] : A[2];
        return (quad & 2) ? x23 : x01;
    };

    auto STEP0 = [&](int rimm, char* wp, const f32x4 (&ini)[4]) {
        const f16x8 a0 = *(const f16x8*)(rdBase + rimm);
        const f16x8 a1 = *(const f16x8*)(rdBase + rimm + 256);
        f32x4 A[4];
        __builtin_amdgcn_s_setprio(1);
#pragma unroll
        for (int g = 0; g < 4; ++g) {
            A[g] = __builtin_amdgcn_mfma_f32_16x16x32_f16(a0, bfA[g][0], ini[g], 0, 0, 0);
            A[g] = __builtin_amdgcn_mfma_f32_16x16x32_f16(a1, bfA[g][1], A[g], 0, 0, 0);
        }
        __builtin_amdgcn_s_setprio(0);
        const float hv = lstm_point(SEL(A[0]), SEL(A[1]), SEL(A[2]), SEL(A[3]), cst);
        *(_Float16*)wp = (_Float16)hv;
    };

    auto STEP1 = [&](int r0imm, int r1imm, char* wp) {
        const f16x8 a0 = *(const f16x8*)(rdBase + r0imm);
        const f16x8 a1 = *(const f16x8*)(rdBase + r0imm + 256);
        const f16x8 a2 = *(const f16x8*)(rdBase + r1imm);
        const f16x8 a3 = *(const f16x8*)(rdBase + r1imm + 256);
        f32x4 Bq[4];
        __builtin_amdgcn_s_setprio(1);
#pragma unroll
        for (int g = 0; g < 4; ++g) {
            Bq[g] = __builtin_amdgcn_mfma_f32_16x16x32_f16(a0, bfB[g][0], cini1[g], 0, 0, 0);
            Bq[g] = __builtin_amdgcn_mfma_f32_16x16x32_f16(a1, bfB[g][1], Bq[g], 0, 0, 0);
            Bq[g] = __builtin_amdgcn_mfma_f32_16x16x32_f16(a2, bfB[g][2], Bq[g], 0, 0, 0);
            Bq[g] = __builtin_amdgcn_mfma_f32_16x16x32_f16(a3, bfB[g][3], Bq[g], 0, 0, 0);
        }
        __builtin_amdgcn_s_setprio(0);
        const float hv = lstm_point(SEL(Bq[0]), SEL(Bq[1]), SEL(Bq[2]), SEL(Bq[3]), cst);
        *(_Float16*)wp = (_Float16)hv;
    };

    auto INI = [&](int t, f32x4 (&ini)[4]) {
        const f32x4 xv = *(const f32x4*)&xl[(t >> 6) & 1][t & 63][0];
#pragma unroll
        for (int g = 0; g < 4; ++g) {
            ini[g][0] = __builtin_fmaf(xv[0], wih0c[g], biasc0[g]);
            ini[g][1] = __builtin_fmaf(xv[1], wih0c[g], biasc0[g]);
            ini[g][2] = __builtin_fmaf(xv[2], wih0c[g], biasc0[g]);
            ini[g][3] = __builtin_fmaf(xv[3], wih0c[g], biasc0[g]);
        }
    };

    f32x4 iniN[4], iniB[4];
    if (RL == 0) INI(1, iniN);

    // ---- steady pairs: (t, t+1) for t = 1,3,...,509; 1 barrier/step ----
    for (int t = 1; t <= 509; t += 2) {
        if (RL == 0) {                         // half A (t odd)
            INI(t + 1, iniB);
            STEP0(0, w0A, iniN);
        } else {
            STEP1(0, 1536, w1A);
        }
        __syncthreads();

        const int tB = t + 1;                  // half B (even)
        if (RL == 0) {
            if ((tB & 63) == 32 && tB < 448) { // stage next x chunk (L0 waves)
                const int cn = (tB >> 6) + 1;
                xl[cn & 1][lane][wid] = x[(b0 + wid) * TSTEPS + cn * 64 + lane];
            }
            INI(t + 2, iniN);
            STEP0(512, w0B, iniB);
        } else {
            STEP1(512, 1024, w1B);
        }
        __syncthreads();
    }

    // ---- t = 511 (half-A parities) ----
    if (RL == 0) STEP0(0, w0A, iniN);
    else         STEP1(0, 1536, w1A);
    __syncthreads();

    // ---- peel t=512: h1(511) only (half-B parities); L1 waves ----
    if (RL == 1) STEP1(512, 1024, w1B);
    __syncthreads();

    // ---- epilogue: h0(511) @ 512, h1(511) @ 1536 ----
    if (tid < 8) {
        const int which = tid >> 2, b = tid & 3;
        const char* hb = Hc + which * 1024 + 512;
        float s = b_fc[0];
        for (int jj = 0; jj < 64; ++jj) {
            const int off = (jj >> 3) * 64 + b * 16 + (jj & 7) * 2;
            s += (float)*(const _Float16*)(hb + off) * W_fc[jj];
        }
        out[which * 1024 + b0 + b] = s;
    }
}

extern "C" void kernel_launch(void* const* d_in, const int* in_sizes, int n_in,
                              void* d_out, int out_size, void* d_ws, size_t ws_size,
                              hipStream_t stream) {
    (void)in_sizes; (void)n_in; (void)d_ws; (void)ws_size; (void)out_size;
    lstm2_kernel<<<256, 512, 0, stream>>>(
        (const float*)d_in[0],
        (const float*)d_in[1], (const float*)d_in[2],
        (const float*)d_in[3], (const float*)d_in[4],
        (const float*)d_in[5], (const float*)d_in[6],
        (const float*)d_in[7], (const float*)d_in[8],
        (const float*)d_in[9], (const float*)d_in[10],
        (float*)d_out);
}